// Round 1
// baseline (1625.402 us; speedup 1.0000x reference)
//
#include <hip/hip_runtime.h>

#define NN 20000      // nodes
#define NE 320000     // edges
#define NB 8          // batch
#define NT 12         // time steps
// H = 64, OUT24 = 24 (HORIZON*F_IN)

__device__ __forceinline__ float bcast(float v, int k) {
  return __int_as_float(__builtin_amdgcn_readlane(__float_as_int(v), k));
}

// ---------------------------------------------------------------- degree
__global__ void deg_kernel(const int* __restrict__ ei, const float* __restrict__ ew,
                           float* __restrict__ wsum_f, float* __restrict__ wsum_b,
                           int* __restrict__ cnt_f, int* __restrict__ cnt_b) {
  int e = blockIdx.x * 256 + threadIdx.x;
  if (e >= NE) return;
  int s = ei[e], t = ei[NE + e];
  float wv = ew[e];
  atomicAdd(&wsum_f[t], wv);
  atomicAdd(&cnt_f[t], 1);
  atomicAdd(&wsum_b[s], wv);
  atomicAdd(&cnt_b[s], 1);
}

// ---------------------------------------------------------------- scan (1 block)
__global__ __launch_bounds__(1024) void scan_kernel(
    const int* __restrict__ cnt_f, const int* __restrict__ cnt_b,
    int* __restrict__ rp_f, int* __restrict__ rp_b,
    int* __restrict__ cur_f, int* __restrict__ cur_b) {
  __shared__ int sm[1024];
  const int tid = threadIdx.x;
  for (int pass = 0; pass < 2; ++pass) {
    const int* cnt = pass ? cnt_b : cnt_f;
    int* rp  = pass ? rp_b  : rp_f;
    int* cur = pass ? cur_b : cur_f;
    int base = tid * 20;
    int s = 0;
    for (int j = 0; j < 20; j++) { int i = base + j; if (i < NN) s += cnt[i]; }
    __syncthreads();            // protect sm reuse across passes
    sm[tid] = s;
    __syncthreads();
    for (int off = 1; off < 1024; off <<= 1) {
      int v = (tid >= off) ? sm[tid - off] : 0;
      __syncthreads();
      sm[tid] += v;
      __syncthreads();
    }
    int run = sm[tid] - s;      // exclusive prefix
    for (int j = 0; j < 20; j++) {
      int i = base + j;
      if (i < NN) { rp[i] = run; cur[i] = run; run += cnt[i]; }
    }
    if (tid == 1023) rp[NN] = sm[1023];
  }
}

// ---------------------------------------------------------------- CSR fill
__global__ void fill_kernel(const int* __restrict__ ei, const float* __restrict__ ew,
                            const float* __restrict__ wsum_f, const float* __restrict__ wsum_b,
                            int* __restrict__ cur_f, int* __restrict__ cur_b,
                            int* __restrict__ col_f, float* __restrict__ wn_f,
                            int* __restrict__ col_b, float* __restrict__ wn_b) {
  int e = blockIdx.x * 256 + threadIdx.x;
  if (e >= NE) return;
  int s = ei[e], t = ei[NE + e];
  float wv = ew[e];
  int slot = atomicAdd(&cur_f[t], 1);
  float w1 = wsum_f[t];
  col_f[slot] = s;
  wn_f[slot] = (w1 > 0.f) ? wv / w1 : 0.f;
  slot = atomicAdd(&cur_b[s], 1);
  float w2 = wsum_b[s];
  col_b[slot] = t;
  wn_b[slot] = (w2 > 0.f) ? wv / w2 : 0.f;
}

// ---------------------------------------------------------------- Wcat = filt_w_i @ dec_w, cb
__global__ void wcat_kernel(const float* __restrict__ filt_w, const float* __restrict__ filt_b,
                            const float* __restrict__ dec_w, const float* __restrict__ dec_b,
                            float* __restrict__ Wcat, float* __restrict__ cbv) {
  int idx = blockIdx.x * 256 + threadIdx.x;
  if (idx < 64 * 128) {
    int k = idx >> 7, j = idx & 127;
    float acc = 0.f;
    if (j < 120) {
      int wi = j / 24, jj = j - wi * 24;
      for (int c = 0; c < 64; c++)
        acc += filt_w[(wi * 64 + k) * 64 + c] * dec_w[c * 24 + jj];
    }
    Wcat[idx] = acc;            // padded [64][128]
  } else if (idx < 64 * 128 + 24) {
    int jj = idx - 64 * 128;
    float acc = dec_b[jj];
    for (int c = 0; c < 64; c++) acc += filt_b[c] * dec_w[c * 24 + jj];
    cbv[jj] = acc;
  }
}

// ---------------------------------------------------------------- nb = (node_emb+enc_b)@w_ih^T + b_ih ; W2 = enc_w@w_ih^T
__global__ __launch_bounds__(512) void nb_kernel(
    const float* __restrict__ node_emb, const float* __restrict__ enc_b,
    const float* __restrict__ w_ih, const float* __restrict__ b_ih,
    const float* __restrict__ enc_w, float* __restrict__ nbuf, float* __restrict__ W2) {
  __shared__ float w3[64 * 64 * 4];
  const int tid = threadIdx.x;
  for (int idx = tid; idx < 192 * 64; idx += 512) {
    int row = idx >> 6, k = idx & 63;
    w3[((k << 6) + (row & 63)) * 4 + (row >> 6)] = w_ih[idx];
  }
  __syncthreads();
  const int lane = tid & 63, wave = tid >> 6;
  const int n = blockIdx.x * 8 + wave;
  float ne = node_emb[n * 64 + lane] + enc_b[lane];
  float ar = b_ih[lane], az = b_ih[64 + lane], an = b_ih[128 + lane];
  const float4* w3v = (const float4*)w3;
#pragma unroll 16
  for (int k = 0; k < 64; k++) {
    float4 w = w3v[(k << 6) + lane];
    float nk = bcast(ne, k);
    ar = fmaf(w.x, nk, ar);
    az = fmaf(w.y, nk, az);
    an = fmaf(w.z, nk, an);
  }
  nbuf[n * 192 + lane] = ar;
  nbuf[n * 192 + 64 + lane] = az;
  nbuf[n * 192 + 128 + lane] = an;
  if (blockIdx.x == 0 && tid < 384) {
    int f = tid / 192, g = tid - f * 192;
    float acc = 0.f;
    for (int k2 = 0; k2 < 64; k2++) acc += enc_w[f * 64 + k2] * w_ih[g * 64 + k2];
    W2[f * 192 + g] = acc;
  }
}

// ---------------------------------------------------------------- fused GRU + 5x(64->24) transform
__global__ __launch_bounds__(512) void gru_kernel(
    const float* __restrict__ x, const float* __restrict__ nbuf,
    const float* __restrict__ W2, const float* __restrict__ b_hh,
    const float* __restrict__ w_hh, const float* __restrict__ Wcat,
    const float* __restrict__ cbv,
    float* __restrict__ G0, float* __restrict__ G1f, float* __restrict__ G2f,
    float* __restrict__ G1b, float* __restrict__ G2b) {
  __shared__ float w3[64 * 64 * 4];   // [k][lane][gate r,z,n,pad] = 64 KB
  const int tid = threadIdx.x;
  for (int idx = tid; idx < 192 * 64; idx += 512) {
    int row = idx >> 6, k = idx & 63;
    w3[((k << 6) + (row & 63)) * 4 + (row >> 6)] = w_hh[idx];
  }
  __syncthreads();

  const int lane = tid & 63;
  const int wave = tid >> 6;
  const int seq0 = blockIdx.x * 64 + wave * 8;

  float nbr[8], nbz[8], nbn[8];
  int xoff[8];
#pragma unroll
  for (int s = 0; s < 8; s++) {
    int seq = seq0 + s;
    int bb = seq / NN;
    int nn = seq - bb * NN;
    xoff[s] = (bb * NT * NN + nn) * 2;
    nbr[s] = nbuf[nn * 192 + lane];
    nbz[s] = nbuf[nn * 192 + 64 + lane];
    nbn[s] = nbuf[nn * 192 + 128 + lane];
  }
  const float W2r0 = W2[lane],       W2z0 = W2[64 + lane],  W2n0 = W2[128 + lane];
  const float W2r1 = W2[192 + lane], W2z1 = W2[256 + lane], W2n1 = W2[320 + lane];
  const float bhr = b_hh[lane], bhz = b_hh[64 + lane], bhn = b_hh[128 + lane];

  float h[8];
#pragma unroll
  for (int s = 0; s < 8; s++) h[s] = 0.f;

  const float4* w3v = (const float4*)w3;

  for (int t = 0; t < NT; t++) {
    float ar[8], az[8], an[8];
#pragma unroll
    for (int s = 0; s < 8; s++) { ar[s] = bhr; az[s] = bhz; an[s] = bhn; }
#pragma unroll 16
    for (int k = 0; k < 64; k++) {
      float4 w = w3v[(k << 6) + lane];
#pragma unroll
      for (int s = 0; s < 8; s++) {
        float hk = bcast(h[s], k);
        ar[s] = fmaf(w.x, hk, ar[s]);
        az[s] = fmaf(w.y, hk, az[s]);
        an[s] = fmaf(w.z, hk, an[s]);
      }
    }
#pragma unroll
    for (int s = 0; s < 8; s++) {
      const float2 xv = *(const float2*)(x + xoff[s] + t * (NN * 2));
      float xr = fmaf(xv.x, W2r0, fmaf(xv.y, W2r1, nbr[s]));
      float xz = fmaf(xv.x, W2z0, fmaf(xv.y, W2z1, nbz[s]));
      float xn = fmaf(xv.x, W2n0, fmaf(xv.y, W2n1, nbn[s]));
      float r = 1.f / (1.f + __expf(-(xr + ar[s])));
      float z = 1.f / (1.f + __expf(-(xz + az[s])));
      float nv = xn + r * an[s];
      float th = 1.f - 2.f / (1.f + __expf(2.f * nv));
      h[s] = (1.f - z) * th + z * h[s];
    }
  }

  // epilogue: g = h @ Wcat (64 -> 120), scatter into the 5 G buffers
  __syncthreads();
  for (int idx = tid; idx < 64 * 128; idx += 512) w3[idx] = Wcat[idx];
  __syncthreads();

  float acc1[8], acc2[8];
#pragma unroll
  for (int s = 0; s < 8; s++) { acc1[s] = 0.f; acc2[s] = 0.f; }
#pragma unroll 16
  for (int k = 0; k < 64; k++) {
    float wA = w3[(k << 7) + lane];
    float wB = w3[(k << 7) + 64 + lane];
#pragma unroll
    for (int s = 0; s < 8; s++) {
      float hk = bcast(h[s], k);
      acc1[s] = fmaf(wA, hk, acc1[s]);
      acc2[s] = fmaf(wB, hk, acc2[s]);
    }
  }
  float cbq = (lane < 24) ? cbv[lane] : 0.f;
  float* b1; int c1;
  if (lane < 24)      { b1 = G0;  c1 = lane; }
  else if (lane < 48) { b1 = G1f; c1 = lane - 24; }
  else                { b1 = G2f; c1 = lane - 48; }
  float* b2 = nullptr; int c2 = 0;
  if (lane < 8)       { b2 = G2f; c2 = 16 + lane; }
  else if (lane < 32) { b2 = G1b; c2 = lane - 8; }
  else if (lane < 56) { b2 = G2b; c2 = lane - 32; }
#pragma unroll
  for (int s = 0; s < 8; s++) {
    int seq = seq0 + s;
    b1[seq * 24 + c1] = acc1[s] + cbq;
    if (b2) b2[seq * 24 + c2] = acc2[s];
  }
}

// ---------------------------------------------------------------- dst = CSR*src + add (24-dim feats)
__global__ __launch_bounds__(192) void prop_kernel(
    const float* __restrict__ src, const float* __restrict__ add,
    float* __restrict__ dst, const int* __restrict__ rp,
    const int* __restrict__ col, const float* __restrict__ wn) {
  const int n = blockIdx.x;
  const int b = threadIdx.x / 24;
  const int j = threadIdx.x - b * 24;
  const int e0 = rp[n], e1 = rp[n + 1];
  float acc = 0.f;
  for (int e = e0; e < e1; ++e) {
    int c = col[e];
    float wv = wn[e];
    acc += wv * src[(b * NN + c) * 24 + j];
  }
  const int o = (b * NN + n) * 24 + j;
  dst[o] = acc + add[o];
}

// ---------------------------------------------------------------- [B,N,24] -> [B,12,N,2]
__global__ void reorder_kernel(const float* __restrict__ G0, float* __restrict__ out) {
  __shared__ float tile[32 * 24];
  const int b = blockIdx.y;
  const int n0 = blockIdx.x * 32;
  const int tid = threadIdx.x;
  for (int idx = tid; idx < 768; idx += 256) tile[idx] = G0[(b * NN + n0) * 24 + idx];
  __syncthreads();
  for (int idx = tid; idx < 768; idx += 256) {
    int f = idx & 1, i = (idx >> 1) & 31, t = idx >> 6;
    out[((b * NT + t) * NN + n0 + i) * 2 + f] = tile[i * 24 + t * 2 + f];
  }
}

// ----------------------------------------------------------------
extern "C" void kernel_launch(void* const* d_in, const int* in_sizes, int n_in,
                              void* d_out, int out_size, void* d_ws, size_t ws_size,
                              hipStream_t stream) {
  const float* x        = (const float*)d_in[0];
  const int*   ei       = (const int*)d_in[1];
  const float* ew       = (const float*)d_in[2];
  const float* enc_w    = (const float*)d_in[3];
  const float* enc_b    = (const float*)d_in[4];
  const float* node_emb = (const float*)d_in[5];
  const float* w_ih     = (const float*)d_in[6];
  const float* w_hh     = (const float*)d_in[7];
  const float* b_ih     = (const float*)d_in[8];
  const float* b_hh     = (const float*)d_in[9];
  const float* filt_w   = (const float*)d_in[10];
  const float* filt_b   = (const float*)d_in[11];
  const float* dec_w    = (const float*)d_in[12];
  const float* dec_b    = (const float*)d_in[13];
  float* out = (float*)d_out;

  char* p = (char*)d_ws;
  auto alloc = [&](size_t bytes) {
    char* r = p;
    p += (bytes + 255) & ~(size_t)255;
    return r;
  };
  const size_t BN24 = (size_t)NB * NN * 24;
  float* G0   = (float*)alloc(BN24 * 4);
  float* G1f  = (float*)alloc(BN24 * 4);
  float* G2f  = (float*)alloc(BN24 * 4);
  float* G1b  = (float*)alloc(BN24 * 4);
  float* G2b  = (float*)alloc(BN24 * 4);
  float* nbuf = (float*)alloc((size_t)NN * 192 * 4);
  int* rp_f   = (int*)alloc((NN + 1) * 4);
  int* rp_b   = (int*)alloc((NN + 1) * 4);
  char* zreg  = alloc(4 * NN * 4);        // wsum_f, wsum_b, cnt_f, cnt_b (zeroed)
  float* wsum_f = (float*)zreg;
  float* wsum_b = wsum_f + NN;
  int*   cnt_f  = (int*)(wsum_b + NN);
  int*   cnt_b  = cnt_f + NN;
  int* cur_f  = (int*)alloc(NN * 4);
  int* cur_b  = (int*)alloc(NN * 4);
  int* col_f  = (int*)alloc((size_t)NE * 4);
  float* wn_f = (float*)alloc((size_t)NE * 4);
  int* col_b  = (int*)alloc((size_t)NE * 4);
  float* wn_b = (float*)alloc((size_t)NE * 4);
  float* Wcat = (float*)alloc(64 * 128 * 4);
  float* cbv  = (float*)alloc(32 * 4);
  float* W2   = (float*)alloc(384 * 4);
  // total ~98.5 MB

  hipMemsetAsync(zreg, 0, 4 * NN * 4, stream);
  deg_kernel<<<(NE + 255) / 256, 256, 0, stream>>>(ei, ew, wsum_f, wsum_b, cnt_f, cnt_b);
  scan_kernel<<<1, 1024, 0, stream>>>(cnt_f, cnt_b, rp_f, rp_b, cur_f, cur_b);
  fill_kernel<<<(NE + 255) / 256, 256, 0, stream>>>(ei, ew, wsum_f, wsum_b, cur_f, cur_b,
                                                    col_f, wn_f, col_b, wn_b);
  wcat_kernel<<<33, 256, 0, stream>>>(filt_w, filt_b, dec_w, dec_b, Wcat, cbv);
  nb_kernel<<<NN / 8, 512, 0, stream>>>(node_emb, enc_b, w_ih, b_ih, enc_w, nbuf, W2);
  gru_kernel<<<(NB * NN) / 64, 512, 0, stream>>>(x, nbuf, W2, b_hh, w_hh, Wcat, cbv,
                                                 G0, G1f, G2f, G1b, G2b);
  // out24 = G0 + P_f(G1f + P_f G2f) + P_b(G1b + P_b G2b)   (all in-place chained)
  prop_kernel<<<NN, 192, 0, stream>>>(G2f, G1f, G1f, rp_f, col_f, wn_f);
  prop_kernel<<<NN, 192, 0, stream>>>(G1f, G0, G0, rp_f, col_f, wn_f);
  prop_kernel<<<NN, 192, 0, stream>>>(G2b, G1b, G1b, rp_b, col_b, wn_b);
  prop_kernel<<<NN, 192, 0, stream>>>(G1b, G0, G0, rp_b, col_b, wn_b);
  reorder_kernel<<<dim3(NN / 32, NB), 256, 0, stream>>>(G0, out);
}

// Round 2
// 888.075 us; speedup vs baseline: 1.8303x; 1.8303x over previous
//
#include <hip/hip_runtime.h>

#define NN 20000      // nodes
#define NE 320000     // edges
#define NB 8          // batch
#define NT 12         // time steps
// H = 64, OUT = 120 (5 hops x 24)

typedef unsigned int u32;
typedef short bf16x8 __attribute__((ext_vector_type(8)));
typedef float f32x4 __attribute__((ext_vector_type(4)));
typedef u32   u32x4 __attribute__((ext_vector_type(4)));

union U8 { u32 u[4]; bf16x8 v; };

__device__ __forceinline__ float bcast(float v, int k) {
  return __int_as_float(__builtin_amdgcn_readlane(__float_as_int(v), k));
}
__device__ __forceinline__ unsigned short f2bf(float f) {
  u32 u = __float_as_uint(f);
  u32 r = (u + 0x7FFFu + ((u >> 16) & 1u)) >> 16;
  return (unsigned short)r;
}
__device__ __forceinline__ float bf2f(unsigned short s) {
  return __uint_as_float(((u32)s) << 16);
}
__device__ __forceinline__ u32 packsplit_hi(float a, float b) {
  return (u32)f2bf(a) | ((u32)f2bf(b) << 16);
}

// ---------------------------------------------------------------- degree
__global__ void deg_kernel(const int* __restrict__ ei, const float* __restrict__ ew,
                           float* __restrict__ wsum_f, float* __restrict__ wsum_b,
                           int* __restrict__ cnt_f, int* __restrict__ cnt_b) {
  int e = blockIdx.x * 256 + threadIdx.x;
  if (e >= NE) return;
  int s = ei[e], t = ei[NE + e];
  float wv = ew[e];
  atomicAdd(&wsum_f[t], wv);
  atomicAdd(&cnt_f[t], 1);
  atomicAdd(&wsum_b[s], wv);
  atomicAdd(&cnt_b[s], 1);
}

// ---------------------------------------------------------------- scan (1 block)
__global__ __launch_bounds__(1024) void scan_kernel(
    const int* __restrict__ cnt_f, const int* __restrict__ cnt_b,
    int* __restrict__ rp_f, int* __restrict__ rp_b,
    int* __restrict__ cur_f, int* __restrict__ cur_b) {
  __shared__ int sm[1024];
  const int tid = threadIdx.x;
  for (int pass = 0; pass < 2; ++pass) {
    const int* cnt = pass ? cnt_b : cnt_f;
    int* rp  = pass ? rp_b  : rp_f;
    int* cur = pass ? cur_b : cur_f;
    int base = tid * 20;
    int s = 0;
    for (int j = 0; j < 20; j++) { int i = base + j; if (i < NN) s += cnt[i]; }
    __syncthreads();
    sm[tid] = s;
    __syncthreads();
    for (int off = 1; off < 1024; off <<= 1) {
      int v = (tid >= off) ? sm[tid - off] : 0;
      __syncthreads();
      sm[tid] += v;
      __syncthreads();
    }
    int run = sm[tid] - s;      // exclusive prefix
    for (int j = 0; j < 20; j++) {
      int i = base + j;
      if (i < NN) { rp[i] = run; cur[i] = run; run += cnt[i]; }
    }
    if (tid == 1023) rp[NN] = sm[1023];
  }
}

// ---------------------------------------------------------------- CSR fill
__global__ void fill_kernel(const int* __restrict__ ei, const float* __restrict__ ew,
                            const float* __restrict__ wsum_f, const float* __restrict__ wsum_b,
                            int* __restrict__ cur_f, int* __restrict__ cur_b,
                            int* __restrict__ col_f, float* __restrict__ wn_f,
                            int* __restrict__ col_b, float* __restrict__ wn_b) {
  int e = blockIdx.x * 256 + threadIdx.x;
  if (e >= NE) return;
  int s = ei[e], t = ei[NE + e];
  float wv = ew[e];
  int slot = atomicAdd(&cur_f[t], 1);
  float w1 = wsum_f[t];
  col_f[slot] = s;
  wn_f[slot] = (w1 > 0.f) ? wv / w1 : 0.f;
  slot = atomicAdd(&cur_b[s], 1);
  float w2 = wsum_b[s];
  col_b[slot] = t;
  wn_b[slot] = (w2 > 0.f) ? wv / w2 : 0.f;
}

// ---------------------------------------------------------------- Wcat = filt_w_i @ dec_w (padded [64][128]), cb
__global__ void wcat_kernel(const float* __restrict__ filt_w, const float* __restrict__ filt_b,
                            const float* __restrict__ dec_w, const float* __restrict__ dec_b,
                            float* __restrict__ Wcat, float* __restrict__ cbv) {
  int idx = blockIdx.x * 256 + threadIdx.x;
  if (idx < 64 * 128) {
    int k = idx >> 7, j = idx & 127;
    float acc = 0.f;
    if (j < 120) {
      int wi = j / 24, jj = j - wi * 24;
      for (int c = 0; c < 64; c++)
        acc += filt_w[(wi * 64 + k) * 64 + c] * dec_w[c * 24 + jj];
    }
    Wcat[idx] = acc;
  } else if (idx < 64 * 128 + 24) {
    int jj = idx - 64 * 128;
    float acc = dec_b[jj];
    for (int c = 0; c < 64; c++) acc += filt_b[c] * dec_w[c * 24 + jj];
    cbv[jj] = acc;
  }
}

// ---------------------------------------------------------------- nbq[q][n][4] (gates r,z merged with b_hh; n x-side only) ; W2 = enc_w@w_ih^T
__global__ __launch_bounds__(512) void nb_kernel(
    const float* __restrict__ node_emb, const float* __restrict__ enc_b,
    const float* __restrict__ w_ih, const float* __restrict__ b_ih,
    const float* __restrict__ enc_w, const float* __restrict__ b_hh,
    float* __restrict__ nbq, float* __restrict__ W2) {
  __shared__ float w3[64 * 64 * 4];
  const int tid = threadIdx.x;
  for (int idx = tid; idx < 192 * 64; idx += 512) {
    int row = idx >> 6, k = idx & 63;
    w3[((k << 6) + (row & 63)) * 4 + (row >> 6)] = w_ih[idx];
  }
  __syncthreads();
  const int lane = tid & 63, wave = tid >> 6;
  const int n = blockIdx.x * 8 + wave;
  float ne = node_emb[n * 64 + lane] + enc_b[lane];
  float ar = b_ih[lane], az = b_ih[64 + lane], an = b_ih[128 + lane];
  const float4* w3v = (const float4*)w3;
#pragma unroll 16
  for (int k = 0; k < 64; k++) {
    float4 w = w3v[(k << 6) + lane];
    float nk = bcast(ne, k);
    ar = fmaf(w.x, nk, ar);
    az = fmaf(w.y, nk, az);
    an = fmaf(w.z, nk, an);
  }
  // layout: q = gt*16 + (f>>2), element f&3; fold b_hh into r,z
  nbq[(((lane >> 2)) * NN + n) * 4 + (lane & 3)]      = ar + b_hh[lane];
  nbq[((16 + (lane >> 2)) * NN + n) * 4 + (lane & 3)] = az + b_hh[64 + lane];
  nbq[((32 + (lane >> 2)) * NN + n) * 4 + (lane & 3)] = an;
  if (blockIdx.x == 0 && tid < 384) {
    int f = tid / 192, g = tid - f * 192;
    float acc = 0.f;
    for (int k2 = 0; k2 < 64; k2++) acc += enc_w[f * 64 + k2] * w_ih[g * 64 + k2];
    W2[f * 192 + g] = acc;
  }
}

// ---------------------------------------------------------------- MFMA GRU + MFMA epilogue
// LDS map (u32 indices):
//   [0 .. 6144)      whh hi frags: [tile12][ks2][lane64][4]
//   [6144 .. 12288)  whh lo frags
//   [12288 .. 16384) h exchange: [wave4][seq16][16 units of 4 u32, XOR-swizzled]
//   epilogue overlays [0..4096) wcat hi, [4096..8192) wcat lo
#define MFMA(acc, a, b) acc = __builtin_amdgcn_mfma_f32_16x16x32_bf16((a), (b), acc, 0, 0, 0)

__global__ __launch_bounds__(256) void gru_kernel(
    const float* __restrict__ x, const float* __restrict__ nbq,
    const float* __restrict__ W2, const float* __restrict__ b_hh,
    const float* __restrict__ w_hh, const float* __restrict__ Wcat,
    const float* __restrict__ cbv,
    float* __restrict__ G0, float* __restrict__ G1f, float* __restrict__ G2f,
    float* __restrict__ G1b, float* __restrict__ G2b) {
  __shared__ u32 lds[16384];
  const int tid = threadIdx.x;

  // ---- build w_hh hi/lo fragment tables (A-frag: row=gate&15, k=(lane>>4)*8+j)
  for (int e = tid; e < 6144; e += 256) {
    int gate = e >> 5, k2 = (e & 31) << 1;
    float w0 = w_hh[gate * 64 + k2];
    float w1 = w_hh[gate * 64 + k2 + 1];
    unsigned short h0 = f2bf(w0), h1 = f2bf(w1);
    unsigned short l0 = f2bf(w0 - bf2f(h0)), l1 = f2bf(w1 - bf2f(h1));
    int tile = gate >> 4, ks = k2 >> 5;
    int ln = (gate & 15) + (((k2 >> 3) & 3) << 4);
    int r = (k2 >> 1) & 3;
    int idx = ((tile * 2 + ks) << 8) + (ln << 2) + r;
    lds[idx]        = (u32)h0 | ((u32)h1 << 16);
    lds[6144 + idx] = (u32)l0 | ((u32)l1 << 16);
  }
  __syncthreads();

  const int lane = tid & 63, wave = tid >> 6;
  const int g = lane >> 4, sl = lane & 15;
  const int seq = blockIdx.x * 64 + wave * 16 + sl;
  const int bb = seq / NN;
  const int node = seq - bb * NN;
  const u32 hexbase = 12288 + wave * 1024 + sl * 64;

  // W2 (x-side weights) per-lane regs: lanes<16 carry k=0,1; others zero
  u32 w2h[12], w2l[12];
#pragma unroll
  for (int tl = 0; tl < 12; tl++) {
    float w0 = W2[tl * 16 + sl], w1 = W2[192 + tl * 16 + sl];
    unsigned short h0 = f2bf(w0), h1 = f2bf(w1);
    u32 ph = (u32)h0 | ((u32)h1 << 16);
    u32 pl = (u32)f2bf(w0 - bf2f(h0)) | ((u32)f2bf(w1 - bf2f(h1)) << 16);
    w2h[tl] = (lane < 16) ? ph : 0u;
    w2l[tl] = (lane < 16) ? pl : 0u;
  }

  // acc inits: nbA=r(+bhh), nbB=z(+bhh), nbC=n(x-side), bhnv=b_hh n-part
  f32x4 nbA[4], nbB[4], nbC[4], bhnv[4];
#pragma unroll
  for (int fb = 0; fb < 4; fb++) {
    nbA[fb]  = *(const f32x4*)(nbq + ((size_t)(fb * 4 + g) * NN + node) * 4);
    nbB[fb]  = *(const f32x4*)(nbq + ((size_t)(16 + fb * 4 + g) * NN + node) * 4);
    nbC[fb]  = *(const f32x4*)(nbq + ((size_t)(32 + fb * 4 + g) * NN + node) * 4);
    bhnv[fb] = *(const f32x4*)(b_hh + 128 + fb * 16 + g * 4);
  }

  f32x4 hreg[4];
#pragma unroll
  for (int fb = 0; fb < 4; fb++) hreg[fb] = (f32x4){0.f, 0.f, 0.f, 0.f};

  const float* xptr = x + ((size_t)(bb * NT) * NN + node) * 2;

#define LDW(tile, ks, part) (*(const bf16x8*)(lds + (part) * 6144 + (((tile) * 2 + (ks)) << 8) + (lane << 2)))
#define RDH(ks, HB, LB) { \
    u32 o0 = hexbase + (((((ks) * 8 + g * 2 + 0)) ^ sl) << 2); \
    u32 o1 = hexbase + (((((ks) * 8 + g * 2 + 1)) ^ sl) << 2); \
    u32x4 qa = *(const u32x4*)(lds + o0); \
    u32x4 qb = *(const u32x4*)(lds + o1); \
    HB.u[0] = (qa.x & 0xffffu) | (qa.y << 16); \
    HB.u[1] = (qa.z & 0xffffu) | (qa.w << 16); \
    HB.u[2] = (qb.x & 0xffffu) | (qb.y << 16); \
    HB.u[3] = (qb.z & 0xffffu) | (qb.w << 16); \
    LB.u[0] = (qa.x >> 16) | (qa.y & 0xffff0000u); \
    LB.u[1] = (qa.z >> 16) | (qa.w & 0xffff0000u); \
    LB.u[2] = (qb.x >> 16) | (qb.y & 0xffff0000u); \
    LB.u[3] = (qb.z >> 16) | (qb.w & 0xffff0000u); \
  }

  U8 hb0, hb1, lb0, lb1;

#pragma unroll 1
  for (int t = 0; t < NT; t++) {
    float2 xv = *(const float2*)(xptr + (size_t)t * (NN * 2));
    unsigned short xh0 = f2bf(xv.x), xh1 = f2bf(xv.y);
    U8 xh, xl;
    xh.u[0] = (u32)xh0 | ((u32)xh1 << 16);
    xl.u[0] = (u32)f2bf(xv.x - bf2f(xh0)) | ((u32)f2bf(xv.y - bf2f(xh1)) << 16);
    xh.u[1] = xh.u[2] = xh.u[3] = 0u;
    xl.u[1] = xl.u[2] = xl.u[3] = 0u;

    if (t) { RDH(0, hb0, lb0); RDH(1, hb1, lb1); }

#pragma unroll
    for (int fb = 0; fb < 4; fb++) {
      f32x4 aR = nbA[fb], aZ = nbB[fb], aXN = nbC[fb], aHN = bhnv[fb];
      if (t) {
        // ks = 0
        bf16x8 AhR = LDW(fb, 0, 0),     AlR = LDW(fb, 0, 1);
        MFMA(aR, AhR, hb0.v); MFMA(aR, AhR, lb0.v); MFMA(aR, AlR, hb0.v);
        bf16x8 AhZ = LDW(4 + fb, 0, 0), AlZ = LDW(4 + fb, 0, 1);
        MFMA(aZ, AhZ, hb0.v); MFMA(aZ, AhZ, lb0.v); MFMA(aZ, AlZ, hb0.v);
        bf16x8 AhN = LDW(8 + fb, 0, 0), AlN = LDW(8 + fb, 0, 1);
        MFMA(aHN, AhN, hb0.v); MFMA(aHN, AhN, lb0.v); MFMA(aHN, AlN, hb0.v);
        // ks = 1
        bf16x8 BhR = LDW(fb, 1, 0),     BlR = LDW(fb, 1, 1);
        MFMA(aR, BhR, hb1.v); MFMA(aR, BhR, lb1.v); MFMA(aR, BlR, hb1.v);
        bf16x8 BhZ = LDW(4 + fb, 1, 0), BlZ = LDW(4 + fb, 1, 1);
        MFMA(aZ, BhZ, hb1.v); MFMA(aZ, BhZ, lb1.v); MFMA(aZ, BlZ, hb1.v);
        bf16x8 BhN = LDW(8 + fb, 1, 0), BlN = LDW(8 + fb, 1, 1);
        MFMA(aHN, BhN, hb1.v); MFMA(aHN, BhN, lb1.v); MFMA(aHN, BlN, hb1.v);
      }
      // x-side (rank-2 via K-extension; A nonzero only lanes<16, k=0,1)
      U8 aWh, aWl;
      aWh.u[1] = aWh.u[2] = aWh.u[3] = 0u;
      aWl.u[1] = aWl.u[2] = aWl.u[3] = 0u;
      aWh.u[0] = w2h[fb];     aWl.u[0] = w2l[fb];
      MFMA(aR, aWh.v, xh.v); MFMA(aR, aWh.v, xl.v); MFMA(aR, aWl.v, xh.v);
      aWh.u[0] = w2h[4 + fb]; aWl.u[0] = w2l[4 + fb];
      MFMA(aZ, aWh.v, xh.v); MFMA(aZ, aWh.v, xl.v); MFMA(aZ, aWl.v, xh.v);
      aWh.u[0] = w2h[8 + fb]; aWl.u[0] = w2l[8 + fb];
      MFMA(aXN, aWh.v, xh.v); MFMA(aXN, aWh.v, xl.v); MFMA(aXN, aWl.v, xh.v);

      // gate math (lane-local), write packed hi|lo h to LDS
      u32x4 pk;
#pragma unroll
      for (int r = 0; r < 4; r++) {
        float rr = 1.f / (1.f + __expf(-aR[r]));
        float zz = 1.f / (1.f + __expf(-aZ[r]));
        float nv = aXN[r] + rr * aHN[r];
        float th = 1.f - 2.f / (1.f + __expf(2.f * nv));
        float h2 = (1.f - zz) * th + zz * hreg[fb][r];
        hreg[fb][r] = h2;
        unsigned short hh = f2bf(h2);
        u32 p = (u32)hh | ((u32)f2bf(h2 - bf2f(hh)) << 16);
        if (r == 0) pk.x = p; else if (r == 1) pk.y = p; else if (r == 2) pk.z = p; else pk.w = p;
      }
      u32 wo = hexbase + ((((fb << 2) + g) ^ sl) << 2);
      *(u32x4*)(lds + wo) = pk;
    }
  }

  // ---- epilogue: out120 = h @ Wcat (3-term split MFMA)
  __syncthreads();   // all waves done with whh frag region
  for (int e = tid; e < 4096; e += 256) {
    int j = e >> 5, k2 = (e & 31) << 1;
    float w0 = Wcat[k2 * 128 + j];
    float w1 = Wcat[(k2 + 1) * 128 + j];
    unsigned short h0 = f2bf(w0), h1 = f2bf(w1);
    unsigned short l0 = f2bf(w0 - bf2f(h0)), l1 = f2bf(w1 - bf2f(h1));
    int tile = j >> 4, ks = k2 >> 5;
    int ln = (j & 15) + (((k2 >> 3) & 3) << 4);
    int r = (k2 >> 1) & 3;
    int idx = ((tile * 2 + ks) << 8) + (ln << 2) + r;
    lds[idx]        = (u32)h0 | ((u32)h1 << 16);
    lds[4096 + idx] = (u32)l0 | ((u32)l1 << 16);
  }
  __syncthreads();
  RDH(0, hb0, lb0);
  RDH(1, hb1, lb1);

#define LDC(tile, ks, part) (*(const bf16x8*)(lds + (part) * 4096 + (((tile) * 2 + (ks)) << 8) + (lane << 2)))
#pragma unroll
  for (int tile = 0; tile < 8; tile++) {
    f32x4 acc = (f32x4){0.f, 0.f, 0.f, 0.f};
    bf16x8 Ah0 = LDC(tile, 0, 0), Al0 = LDC(tile, 0, 1);
    MFMA(acc, Ah0, hb0.v); MFMA(acc, Ah0, lb0.v); MFMA(acc, Al0, hb0.v);
    bf16x8 Ah1 = LDC(tile, 1, 0), Al1 = LDC(tile, 1, 1);
    MFMA(acc, Ah1, hb1.v); MFMA(acc, Ah1, lb1.v); MFMA(acc, Al1, hb1.v);
#pragma unroll
    for (int r = 0; r < 4; r++) {
      int j = tile * 16 + g * 4 + r;
      if (j < 120) {
        int wi = j / 24, jj = j - wi * 24;
        float val = acc[r];
        if (wi == 0) val += cbv[jj];
        float* gb = (wi == 0) ? G0 : (wi == 1) ? G1f : (wi == 2) ? G2f : (wi == 3) ? G1b : G2b;
        gb[(size_t)seq * 24 + jj] = val;
      }
    }
  }
}

// ---------------------------------------------------------------- dst = CSR*src + add (24-dim feats)
__global__ __launch_bounds__(192) void prop_kernel(
    const float* __restrict__ src, const float* __restrict__ add,
    float* __restrict__ dst, const int* __restrict__ rp,
    const int* __restrict__ col, const float* __restrict__ wn) {
  const int n = blockIdx.x;
  const int b = threadIdx.x / 24;
  const int j = threadIdx.x - b * 24;
  const int e0 = rp[n], e1 = rp[n + 1];
  float acc = 0.f;
  for (int e = e0; e < e1; ++e) {
    int c = col[e];
    float wv = wn[e];
    acc += wv * src[(b * NN + c) * 24 + j];
  }
  const int o = (b * NN + n) * 24 + j;
  dst[o] = acc + add[o];
}

// ---------------------------------------------------------------- [B,N,24] -> [B,12,N,2]
__global__ void reorder_kernel(const float* __restrict__ G0, float* __restrict__ out) {
  __shared__ float tile[32 * 24];
  const int b = blockIdx.y;
  const int n0 = blockIdx.x * 32;
  const int tid = threadIdx.x;
  for (int idx = tid; idx < 768; idx += 256) tile[idx] = G0[(b * NN + n0) * 24 + idx];
  __syncthreads();
  for (int idx = tid; idx < 768; idx += 256) {
    int f = idx & 1, i = (idx >> 1) & 31, t = idx >> 6;
    out[((b * NT + t) * NN + n0 + i) * 2 + f] = tile[i * 24 + t * 2 + f];
  }
}

// ----------------------------------------------------------------
extern "C" void kernel_launch(void* const* d_in, const int* in_sizes, int n_in,
                              void* d_out, int out_size, void* d_ws, size_t ws_size,
                              hipStream_t stream) {
  const float* x        = (const float*)d_in[0];
  const int*   ei       = (const int*)d_in[1];
  const float* ew       = (const float*)d_in[2];
  const float* enc_w    = (const float*)d_in[3];
  const float* enc_b    = (const float*)d_in[4];
  const float* node_emb = (const float*)d_in[5];
  const float* w_ih     = (const float*)d_in[6];
  const float* w_hh     = (const float*)d_in[7];
  const float* b_ih     = (const float*)d_in[8];
  const float* b_hh     = (const float*)d_in[9];
  const float* filt_w   = (const float*)d_in[10];
  const float* filt_b   = (const float*)d_in[11];
  const float* dec_w    = (const float*)d_in[12];
  const float* dec_b    = (const float*)d_in[13];
  float* out = (float*)d_out;

  char* p = (char*)d_ws;
  auto alloc = [&](size_t bytes) {
    char* r = p;
    p += (bytes + 255) & ~(size_t)255;
    return r;
  };
  const size_t BN24 = (size_t)NB * NN * 24;
  float* G0   = (float*)alloc(BN24 * 4);
  float* G1f  = (float*)alloc(BN24 * 4);
  float* G2f  = (float*)alloc(BN24 * 4);
  float* G1b  = (float*)alloc(BN24 * 4);
  float* G2b  = (float*)alloc(BN24 * 4);
  float* nbq  = (float*)alloc((size_t)NN * 192 * 4);
  int* rp_f   = (int*)alloc((NN + 1) * 4);
  int* rp_b   = (int*)alloc((NN + 1) * 4);
  char* zreg  = alloc(4 * NN * 4);        // wsum_f, wsum_b, cnt_f, cnt_b (zeroed)
  float* wsum_f = (float*)zreg;
  float* wsum_b = wsum_f + NN;
  int*   cnt_f  = (int*)(wsum_b + NN);
  int*   cnt_b  = cnt_f + NN;
  int* cur_f  = (int*)alloc(NN * 4);
  int* cur_b  = (int*)alloc(NN * 4);
  int* col_f  = (int*)alloc((size_t)NE * 4);
  float* wn_f = (float*)alloc((size_t)NE * 4);
  int* col_b  = (int*)alloc((size_t)NE * 4);
  float* wn_b = (float*)alloc((size_t)NE * 4);
  float* Wcat = (float*)alloc(64 * 128 * 4);
  float* cbv  = (float*)alloc(32 * 4);
  float* W2   = (float*)alloc(384 * 4);

  hipMemsetAsync(zreg, 0, 4 * NN * 4, stream);
  deg_kernel<<<(NE + 255) / 256, 256, 0, stream>>>(ei, ew, wsum_f, wsum_b, cnt_f, cnt_b);
  scan_kernel<<<1, 1024, 0, stream>>>(cnt_f, cnt_b, rp_f, rp_b, cur_f, cur_b);
  fill_kernel<<<(NE + 255) / 256, 256, 0, stream>>>(ei, ew, wsum_f, wsum_b, cur_f, cur_b,
                                                    col_f, wn_f, col_b, wn_b);
  wcat_kernel<<<33, 256, 0, stream>>>(filt_w, filt_b, dec_w, dec_b, Wcat, cbv);
  nb_kernel<<<NN / 8, 512, 0, stream>>>(node_emb, enc_b, w_ih, b_ih, enc_w, b_hh, nbq, W2);
  gru_kernel<<<(NB * NN) / 64, 256, 0, stream>>>(x, nbq, W2, b_hh, w_hh, Wcat, cbv,
                                                 G0, G1f, G2f, G1b, G2b);
  // out24 = G0 + P_f(G1f + P_f G2f) + P_b(G1b + P_b G2b)
  prop_kernel<<<NN, 192, 0, stream>>>(G2f, G1f, G1f, rp_f, col_f, wn_f);
  prop_kernel<<<NN, 192, 0, stream>>>(G1f, G0, G0, rp_f, col_f, wn_f);
  prop_kernel<<<NN, 192, 0, stream>>>(G2b, G1b, G1b, rp_b, col_b, wn_b);
  prop_kernel<<<NN, 192, 0, stream>>>(G1b, G0, G0, rp_b, col_b, wn_b);
  reorder_kernel<<<dim3(NN / 32, NB), 256, 0, stream>>>(G0, out);
}

// Round 3
// 663.205 us; speedup vs baseline: 2.4508x; 1.3391x over previous
//
#include <hip/hip_runtime.h>

#define NN 20000      // nodes
#define NE 320000     // edges
#define NB 8          // batch
#define NT 12         // time steps
// H = 64, OUT = 120 (5 hops x 24), G layout node-major: G[(n*NB+b)*24 + j]

typedef unsigned int u32;
typedef short bf16x8 __attribute__((ext_vector_type(8)));
typedef float f32x4 __attribute__((ext_vector_type(4)));
typedef u32   u32x2 __attribute__((ext_vector_type(2)));

union U8 { u32 u[4]; bf16x8 v; };

__device__ __forceinline__ float bcast(float v, int k) {
  return __int_as_float(__builtin_amdgcn_readlane(__float_as_int(v), k));
}
// dst = { lo16 = bf16(a), hi16 = bf16(b) }  (RNE, hardware)
__device__ __forceinline__ u32 cvt_pk_bf16(float a, float b) {
  u32 r;
  asm("v_cvt_pk_bf16_f32 %0, %1, %2" : "=v"(r) : "v"(a), "v"(b));
  return r;
}
__device__ __forceinline__ float rcpf(float x) {
  float r;
  asm("v_rcp_f32 %0, %1" : "=v"(r) : "v"(x));
  return r;
}
__device__ __forceinline__ unsigned short f2bf(float f) {
  u32 u = __float_as_uint(f);
  u32 r = (u + 0x7FFFu + ((u >> 16) & 1u)) >> 16;
  return (unsigned short)r;
}
__device__ __forceinline__ float bf2f(unsigned short s) {
  return __uint_as_float(((u32)s) << 16);
}

// ---------------------------------------------------------------- degree
__global__ void deg_kernel(const int* __restrict__ ei, const float* __restrict__ ew,
                           float* __restrict__ wsum_f, float* __restrict__ wsum_b,
                           int* __restrict__ cnt_f, int* __restrict__ cnt_b) {
  int e = blockIdx.x * 256 + threadIdx.x;
  if (e >= NE) return;
  int s = ei[e], t = ei[NE + e];
  float wv = ew[e];
  atomicAdd(&wsum_f[t], wv);
  atomicAdd(&cnt_f[t], 1);
  atomicAdd(&wsum_b[s], wv);
  atomicAdd(&cnt_b[s], 1);
}

// ---------------------------------------------------------------- scan (1 block, int4)
__global__ __launch_bounds__(1024) void scan_kernel(
    const int* __restrict__ cnt_f, const int* __restrict__ cnt_b,
    int* __restrict__ rp_f, int* __restrict__ rp_b,
    int* __restrict__ cur_f, int* __restrict__ cur_b) {
  __shared__ int sm[1024];
  const int tid = threadIdx.x;
  for (int pass = 0; pass < 2; ++pass) {
    const int* cnt = pass ? cnt_b : cnt_f;
    int* rp  = pass ? rp_b  : rp_f;
    int* cur = pass ? cur_b : cur_f;
    const int base = tid * 20;
    int4 c4[5];
    int s = 0;
    if (base < NN) {
      const int4* cp = (const int4*)(cnt + base);
#pragma unroll
      for (int j = 0; j < 5; j++) c4[j] = cp[j];
#pragma unroll
      for (int j = 0; j < 5; j++) s += c4[j].x + c4[j].y + c4[j].z + c4[j].w;
    }
    __syncthreads();
    sm[tid] = s;
    __syncthreads();
    for (int off = 1; off < 1024; off <<= 1) {
      int v = (tid >= off) ? sm[tid - off] : 0;
      __syncthreads();
      sm[tid] += v;
      __syncthreads();
    }
    if (base < NN) {
      int run = sm[tid] - s;
      int4* rp4  = (int4*)(rp + base);
      int4* cur4 = (int4*)(cur + base);
#pragma unroll
      for (int j = 0; j < 5; j++) {
        int4 o;
        o.x = run; run += c4[j].x;
        o.y = run; run += c4[j].y;
        o.z = run; run += c4[j].z;
        o.w = run; run += c4[j].w;
        rp4[j] = o;
        cur4[j] = o;
      }
    }
    if (tid == 1023) rp[NN] = sm[1023];
  }
}

// ---------------------------------------------------------------- CSR fill
__global__ void fill_kernel(const int* __restrict__ ei, const float* __restrict__ ew,
                            const float* __restrict__ wsum_f, const float* __restrict__ wsum_b,
                            int* __restrict__ cur_f, int* __restrict__ cur_b,
                            int* __restrict__ col_f, float* __restrict__ wn_f,
                            int* __restrict__ col_b, float* __restrict__ wn_b) {
  int e = blockIdx.x * 256 + threadIdx.x;
  if (e >= NE) return;
  int s = ei[e], t = ei[NE + e];
  float wv = ew[e];
  int slot = atomicAdd(&cur_f[t], 1);
  float w1 = wsum_f[t];
  col_f[slot] = s;
  wn_f[slot] = (w1 > 0.f) ? wv / w1 : 0.f;
  slot = atomicAdd(&cur_b[s], 1);
  float w2 = wsum_b[s];
  col_b[slot] = t;
  wn_b[slot] = (w2 > 0.f) ? wv / w2 : 0.f;
}

// ---------------------------------------------------------------- nbq + W2 + (wcat in tail blocks)
__global__ __launch_bounds__(512) void nb_kernel(
    const float* __restrict__ node_emb, const float* __restrict__ enc_b,
    const float* __restrict__ w_ih, const float* __restrict__ b_ih,
    const float* __restrict__ enc_w, const float* __restrict__ b_hh,
    const float* __restrict__ filt_w, const float* __restrict__ filt_b,
    const float* __restrict__ dec_w, const float* __restrict__ dec_b,
    float* __restrict__ nbq, float* __restrict__ W2,
    float* __restrict__ Wcat, float* __restrict__ cbv) {
  const int tid = threadIdx.x;
  if (blockIdx.x >= NN / 8) {
    // ---- wcat part: Wcat[64][128] = filt_w_i @ dec_w (padded), cbv
    int idx = (blockIdx.x - NN / 8) * 512 + tid;
    if (idx < 64 * 128) {
      int k = idx >> 7, j = idx & 127;
      float acc = 0.f;
      if (j < 120) {
        int wi = j / 24, jj = j - wi * 24;
        for (int c = 0; c < 64; c++)
          acc += filt_w[(wi * 64 + k) * 64 + c] * dec_w[c * 24 + jj];
      }
      Wcat[idx] = acc;
    } else if (idx < 64 * 128 + 24) {
      int jj = idx - 64 * 128;
      float acc = dec_b[jj];
      for (int c = 0; c < 64; c++) acc += filt_b[c] * dec_w[c * 24 + jj];
      cbv[jj] = acc;
    }
    return;
  }
  __shared__ float w3[64 * 64 * 4];
  for (int idx = tid; idx < 192 * 64; idx += 512) {
    int row = idx >> 6, k = idx & 63;
    w3[((k << 6) + (row & 63)) * 4 + (row >> 6)] = w_ih[idx];
  }
  __syncthreads();
  const int lane = tid & 63, wave = tid >> 6;
  const int n = blockIdx.x * 8 + wave;
  float ne = node_emb[n * 64 + lane] + enc_b[lane];
  float ar = b_ih[lane], az = b_ih[64 + lane], an = b_ih[128 + lane];
  const float4* w3v = (const float4*)w3;
#pragma unroll 16
  for (int k = 0; k < 64; k++) {
    float4 w = w3v[(k << 6) + lane];
    float nk = bcast(ne, k);
    ar = fmaf(w.x, nk, ar);
    az = fmaf(w.y, nk, az);
    an = fmaf(w.z, nk, an);
  }
  // layout: q = gt*16 + (f>>2), element f&3; fold b_hh into r,z
  nbq[(((lane >> 2)) * NN + n) * 4 + (lane & 3)]      = ar + b_hh[lane];
  nbq[((16 + (lane >> 2)) * NN + n) * 4 + (lane & 3)] = az + b_hh[64 + lane];
  nbq[((32 + (lane >> 2)) * NN + n) * 4 + (lane & 3)] = an;
  if (blockIdx.x == 0 && tid < 384) {
    int f = tid / 192, g = tid - f * 192;
    float acc = 0.f;
    for (int k2 = 0; k2 < 64; k2++) acc += enc_w[f * 64 + k2] * w_ih[g * 64 + k2];
    W2[f * 192 + g] = acc;
  }
}

// ---------------------------------------------------------------- MFMA GRU + MFMA epilogue
// LDS map (u32 idx): [0,6144) whh-hi frags; [6144,12288) whh-lo frags;
// [12288,16384) h-exchange: wave*1024 + sl*64 + plane*32 + (pairidx ^ ((sl&7)<<2))
// epilogue overlays [0,4096) wcat-hi, [4096,8192) wcat-lo.
#define MFMA(acc, a, b) acc = __builtin_amdgcn_mfma_f32_16x16x32_bf16((a), (b), acc, 0, 0, 0)

__global__ __launch_bounds__(256) void gru_kernel(
    const float* __restrict__ x, const float* __restrict__ nbq,
    const float* __restrict__ W2, const float* __restrict__ b_hh,
    const float* __restrict__ w_hh, const float* __restrict__ Wcat,
    const float* __restrict__ cbv,
    float* __restrict__ G0, float* __restrict__ G1f, float* __restrict__ G2f,
    float* __restrict__ G1b, float* __restrict__ G2b) {
  __shared__ u32 lds[16384];
  const int tid = threadIdx.x;

  // ---- whh hi/lo A-frag tables (row=gate&15, k=(lane>>4)*8+j)
  for (int e = tid; e < 6144; e += 256) {
    int gate = e >> 5, k2 = (e & 31) << 1;
    float w0 = w_hh[gate * 64 + k2];
    float w1 = w_hh[gate * 64 + k2 + 1];
    unsigned short h0 = f2bf(w0), h1 = f2bf(w1);
    unsigned short l0 = f2bf(w0 - bf2f(h0)), l1 = f2bf(w1 - bf2f(h1));
    int tile = gate >> 4, ks = k2 >> 5;
    int ln = (gate & 15) + (((k2 >> 3) & 3) << 4);
    int r = (k2 >> 1) & 3;
    int idx = ((tile * 2 + ks) << 8) + (ln << 2) + r;
    lds[idx]        = (u32)h0 | ((u32)h1 << 16);
    lds[6144 + idx] = (u32)l0 | ((u32)l1 << 16);
  }
  __syncthreads();

  const int lane = tid & 63, wave = tid >> 6;
  const int g = lane >> 4, sl = lane & 15;
  const int seq = blockIdx.x * 64 + wave * 16 + sl;
  const int bb = seq / NN;
  const int node = seq - bb * NN;
  const u32 hxbase = 12288 + wave * 1024 + sl * 64;
  const u32 xw = ((u32)(sl & 7)) << 2;

  // W2 (x-side) per-lane regs: lanes<16 carry k=0,1; others zero
  u32 w2h[12], w2l[12];
#pragma unroll
  for (int tl = 0; tl < 12; tl++) {
    float w0 = W2[tl * 16 + sl], w1 = W2[192 + tl * 16 + sl];
    u32 ph = cvt_pk_bf16(w0, w1);
    float lo0 = w0 - __uint_as_float(ph << 16);
    float lo1 = w1 - __uint_as_float(ph & 0xffff0000u);
    u32 pl = cvt_pk_bf16(lo0, lo1);
    w2h[tl] = (lane < 16) ? ph : 0u;
    w2l[tl] = (lane < 16) ? pl : 0u;
  }

  // acc inits: nbA=r(+bhh), nbB=z(+bhh), nbC=n(x-side), bhnv=b_hh n-part
  f32x4 nbA[4], nbB[4], nbC[4], bhnv[4];
#pragma unroll
  for (int fb = 0; fb < 4; fb++) {
    nbA[fb]  = *(const f32x4*)(nbq + ((size_t)(fb * 4 + g) * NN + node) * 4);
    nbB[fb]  = *(const f32x4*)(nbq + ((size_t)(16 + fb * 4 + g) * NN + node) * 4);
    nbC[fb]  = *(const f32x4*)(nbq + ((size_t)(32 + fb * 4 + g) * NN + node) * 4);
    bhnv[fb] = *(const f32x4*)(b_hh + 128 + fb * 16 + g * 4);
  }

  f32x4 hreg[4];
#pragma unroll
  for (int fb = 0; fb < 4; fb++) hreg[fb] = (f32x4){0.f, 0.f, 0.f, 0.f};

  const float* xptr = x + ((size_t)(bb * NT) * NN + node) * 2;

#define LDW(tile, ks, part) (*(const bf16x8*)(lds + (part) * 6144 + (((tile) * 2 + (ks)) << 8) + (lane << 2)))

  bf16x8 hb0, hb1, lb0, lb1;

#pragma unroll 1
  for (int t = 0; t < NT; t++) {
    // x B-frag: k01=xh, k23=xl, k45=xh (garbage in lanes g>0 is killed by A=0)
    float2 xv = *(const float2*)(xptr + (size_t)t * (NN * 2));
    u32 xhw = cvt_pk_bf16(xv.x, xv.y);
    float xl0 = xv.x - __uint_as_float(xhw << 16);
    float xl1 = xv.y - __uint_as_float(xhw & 0xffff0000u);
    u32 xlw = cvt_pk_bf16(xl0, xl1);
    U8 xB;
    xB.u[0] = xhw; xB.u[1] = xlw; xB.u[2] = xhw; xB.u[3] = 0u;

    if (t) {
      hb0 = *(const bf16x8*)(lds + hxbase +      ((u32)(0  + g * 4) ^ xw));
      hb1 = *(const bf16x8*)(lds + hxbase +      ((u32)(16 + g * 4) ^ xw));
      lb0 = *(const bf16x8*)(lds + hxbase + 32 + ((u32)(0  + g * 4) ^ xw));
      lb1 = *(const bf16x8*)(lds + hxbase + 32 + ((u32)(16 + g * 4) ^ xw));
    }

#pragma unroll
    for (int fb = 0; fb < 4; fb++) {
      f32x4 aR = nbA[fb], aZ = nbB[fb], aXN = nbC[fb], aHN = bhnv[fb];
      if (t) {
        bf16x8 Ah0 = LDW(fb, 0, 0), Al0 = LDW(fb, 0, 1);
        bf16x8 Ah1 = LDW(fb, 1, 0), Al1 = LDW(fb, 1, 1);
        MFMA(aR, Ah0, hb0); MFMA(aR, Ah0, lb0); MFMA(aR, Al0, hb0);
        MFMA(aR, Ah1, hb1); MFMA(aR, Ah1, lb1); MFMA(aR, Al1, hb1);
        bf16x8 Bh0 = LDW(4 + fb, 0, 0), Bl0 = LDW(4 + fb, 0, 1);
        bf16x8 Bh1 = LDW(4 + fb, 1, 0), Bl1 = LDW(4 + fb, 1, 1);
        MFMA(aZ, Bh0, hb0); MFMA(aZ, Bh0, lb0); MFMA(aZ, Bl0, hb0);
        MFMA(aZ, Bh1, hb1); MFMA(aZ, Bh1, lb1); MFMA(aZ, Bl1, hb1);
        bf16x8 Ch0 = LDW(8 + fb, 0, 0), Cl0 = LDW(8 + fb, 0, 1);
        bf16x8 Ch1 = LDW(8 + fb, 1, 0), Cl1 = LDW(8 + fb, 1, 1);
        MFMA(aHN, Ch0, hb0); MFMA(aHN, Ch0, lb0); MFMA(aHN, Cl0, hb0);
        MFMA(aHN, Ch1, hb1); MFMA(aHN, Ch1, lb1); MFMA(aHN, Cl1, hb1);
      }
      // x-side: one MFMA per gate (3-term split packed along K)
      U8 aW;
      aW.u[0] = w2h[fb];     aW.u[1] = w2h[fb];     aW.u[2] = w2l[fb];     aW.u[3] = 0u;
      MFMA(aR, aW.v, xB.v);
      aW.u[0] = w2h[4 + fb]; aW.u[1] = w2h[4 + fb]; aW.u[2] = w2l[4 + fb];
      MFMA(aZ, aW.v, xB.v);
      aW.u[0] = w2h[8 + fb]; aW.u[1] = w2h[8 + fb]; aW.u[2] = w2l[8 + fb];
      MFMA(aXN, aW.v, xB.v);

      // gate math (lane-local), pack h hi/lo planes
      float hv[4];
#pragma unroll
      for (int r = 0; r < 4; r++) {
        float rr = rcpf(1.f + __expf(-aR[r]));
        float zz = rcpf(1.f + __expf(-aZ[r]));
        float nv = fmaf(rr, aHN[r], aXN[r]);
        float th = fmaf(-2.f, rcpf(1.f + __expf(2.f * nv)), 1.f);
        float h2 = fmaf(zz, hreg[fb][r] - th, th);
        hreg[fb][r] = h2;
        hv[r] = h2;
      }
      u32 hiA = cvt_pk_bf16(hv[0], hv[1]);
      u32 hiB = cvt_pk_bf16(hv[2], hv[3]);
      float l0 = hv[0] - __uint_as_float(hiA << 16);
      float l1 = hv[1] - __uint_as_float(hiA & 0xffff0000u);
      float l2 = hv[2] - __uint_as_float(hiB << 16);
      float l3 = hv[3] - __uint_as_float(hiB & 0xffff0000u);
      u32 loA = cvt_pk_bf16(l0, l1);
      u32 loB = cvt_pk_bf16(l2, l3);
      u32 off = hxbase + ((u32)(fb * 8 + g * 2) ^ xw);
      *(u32x2*)(lds + off)      = (u32x2){hiA, hiB};
      *(u32x2*)(lds + off + 32) = (u32x2){loA, loB};
    }
  }

  // ---- epilogue: out120 = h @ Wcat (3-term split MFMA)
  __syncthreads();   // all waves done with whh frag region
  for (int e = tid; e < 4096; e += 256) {
    int j = e >> 5, k2 = (e & 31) << 1;
    float w0 = Wcat[k2 * 128 + j];
    float w1 = Wcat[(k2 + 1) * 128 + j];
    unsigned short h0 = f2bf(w0), h1 = f2bf(w1);
    unsigned short l0 = f2bf(w0 - bf2f(h0)), l1 = f2bf(w1 - bf2f(h1));
    int tile = j >> 4, ks = k2 >> 5;
    int ln = (j & 15) + (((k2 >> 3) & 3) << 4);
    int r = (k2 >> 1) & 3;
    int idx = ((tile * 2 + ks) << 8) + (ln << 2) + r;
    lds[idx]        = (u32)h0 | ((u32)h1 << 16);
    lds[4096 + idx] = (u32)l0 | ((u32)l1 << 16);
  }
  __syncthreads();
  hb0 = *(const bf16x8*)(lds + hxbase +      ((u32)(0  + g * 4) ^ xw));
  hb1 = *(const bf16x8*)(lds + hxbase +      ((u32)(16 + g * 4) ^ xw));
  lb0 = *(const bf16x8*)(lds + hxbase + 32 + ((u32)(0  + g * 4) ^ xw));
  lb1 = *(const bf16x8*)(lds + hxbase + 32 + ((u32)(16 + g * 4) ^ xw));

#define LDC(tile, ks, part) (*(const bf16x8*)(lds + (part) * 4096 + (((tile) * 2 + (ks)) << 8) + (lane << 2)))
#pragma unroll
  for (int tile = 0; tile < 8; tile++) {
    f32x4 acc = (f32x4){0.f, 0.f, 0.f, 0.f};
    bf16x8 Ah0 = LDC(tile, 0, 0), Al0 = LDC(tile, 0, 1);
    MFMA(acc, Ah0, hb0); MFMA(acc, Ah0, lb0); MFMA(acc, Al0, hb0);
    bf16x8 Ah1 = LDC(tile, 1, 0), Al1 = LDC(tile, 1, 1);
    MFMA(acc, Ah1, hb1); MFMA(acc, Ah1, lb1); MFMA(acc, Al1, hb1);
#pragma unroll
    for (int r = 0; r < 4; r++) {
      int j = tile * 16 + g * 4 + r;
      if (j < 120) {
        int wi = j / 24, jj = j - wi * 24;
        float val = acc[r];
        if (wi == 0) val += cbv[jj];
        float* gb = (wi == 0) ? G0 : (wi == 1) ? G1f : (wi == 2) ? G2f : (wi == 3) ? G1b : G2b;
        gb[((size_t)node * NB + bb) * 24 + jj] = val;   // node-major
      }
    }
  }
}

// ---------------------------------------------------------------- hop1: G1f += Pf G2f  |  G1b += Pb G2b
__global__ __launch_bounds__(192) void hop1_kernel(
    float* __restrict__ G1f, const float* __restrict__ G2f,
    float* __restrict__ G1b, const float* __restrict__ G2b,
    const int* __restrict__ rp_f, const int* __restrict__ col_f, const float* __restrict__ wn_f,
    const int* __restrict__ rp_b, const int* __restrict__ col_b, const float* __restrict__ wn_b) {
  const int tid = threadIdx.x;
  int blk = blockIdx.x;
  const int* rp; const int* col; const float* wn; float* dst; const float* src;
  int n;
  if (blk < NN) { n = blk;      rp = rp_f; col = col_f; wn = wn_f; dst = G1f; src = G2f; }
  else          { n = blk - NN; rp = rp_b; col = col_b; wn = wn_b; dst = G1b; src = G2b; }
  const int e0 = rp[n], e1 = rp[n + 1];
  float acc = 0.f;
  for (int e = e0; e < e1; ++e)
    acc = fmaf(wn[e], src[(size_t)col[e] * 192 + tid], acc);
  dst[(size_t)n * 192 + tid] += acc;
}

// ---------------------------------------------------------------- hop2: G0 += Pf G1f + Pb G1b
__global__ __launch_bounds__(192) void hop2_kernel(
    float* __restrict__ G0, const float* __restrict__ G1f, const float* __restrict__ G1b,
    const int* __restrict__ rp_f, const int* __restrict__ col_f, const float* __restrict__ wn_f,
    const int* __restrict__ rp_b, const int* __restrict__ col_b, const float* __restrict__ wn_b) {
  const int tid = threadIdx.x;
  const int n = blockIdx.x;
  float acc = G0[(size_t)n * 192 + tid];
  int e0 = rp_f[n], e1 = rp_f[n + 1];
  for (int e = e0; e < e1; ++e)
    acc = fmaf(wn_f[e], G1f[(size_t)col_f[e] * 192 + tid], acc);
  e0 = rp_b[n]; e1 = rp_b[n + 1];
  for (int e = e0; e < e1; ++e)
    acc = fmaf(wn_b[e], G1b[(size_t)col_b[e] * 192 + tid], acc);
  G0[(size_t)n * 192 + tid] = acc;
}

// ---------------------------------------------------------------- G0[n][b][24] -> out[b][t][n][f]
__global__ __launch_bounds__(256) void reorder_kernel(const float* __restrict__ G0,
                                                      float* __restrict__ out) {
  __shared__ float tile[32 * 193];
  const int n0 = blockIdx.x * 32;
  const int tid = threadIdx.x;
  for (int idx = tid; idx < 6144; idx += 256) {
    int i = idx / 192, r = idx - i * 192;
    tile[i * 193 + r] = G0[(size_t)n0 * 192 + idx];
  }
  __syncthreads();
  for (int idx = tid; idx < 6144; idx += 256) {
    int b = idx / 768;
    int rem = idx - b * 768;
    int t = rem >> 6;
    int rem2 = rem & 63;
    int i = rem2 >> 1, f = rem2 & 1;
    out[(((size_t)b * NT + t) * NN + n0 + i) * 2 + f] = tile[i * 193 + b * 24 + t * 2 + f];
  }
}

// ----------------------------------------------------------------
extern "C" void kernel_launch(void* const* d_in, const int* in_sizes, int n_in,
                              void* d_out, int out_size, void* d_ws, size_t ws_size,
                              hipStream_t stream) {
  const float* x        = (const float*)d_in[0];
  const int*   ei       = (const int*)d_in[1];
  const float* ew       = (const float*)d_in[2];
  const float* enc_w    = (const float*)d_in[3];
  const float* enc_b    = (const float*)d_in[4];
  const float* node_emb = (const float*)d_in[5];
  const float* w_ih     = (const float*)d_in[6];
  const float* w_hh     = (const float*)d_in[7];
  const float* b_ih     = (const float*)d_in[8];
  const float* b_hh     = (const float*)d_in[9];
  const float* filt_w   = (const float*)d_in[10];
  const float* filt_b   = (const float*)d_in[11];
  const float* dec_w    = (const float*)d_in[12];
  const float* dec_b    = (const float*)d_in[13];
  float* out = (float*)d_out;

  char* p = (char*)d_ws;
  auto alloc = [&](size_t bytes) {
    char* r = p;
    p += (bytes + 255) & ~(size_t)255;
    return r;
  };
  const size_t BN24 = (size_t)NB * NN * 24;
  float* G0   = (float*)alloc(BN24 * 4);
  float* G1f  = (float*)alloc(BN24 * 4);
  float* G2f  = (float*)alloc(BN24 * 4);
  float* G1b  = (float*)alloc(BN24 * 4);
  float* G2b  = (float*)alloc(BN24 * 4);
  float* nbq  = (float*)alloc((size_t)NN * 192 * 4);
  int* rp_f   = (int*)alloc((NN + 1) * 4);
  int* rp_b   = (int*)alloc((NN + 1) * 4);
  char* zreg  = alloc(4 * NN * 4);        // wsum_f, wsum_b, cnt_f, cnt_b (zeroed)
  float* wsum_f = (float*)zreg;
  float* wsum_b = wsum_f + NN;
  int*   cnt_f  = (int*)(wsum_b + NN);
  int*   cnt_b  = cnt_f + NN;
  int* cur_f  = (int*)alloc(NN * 4);
  int* cur_b  = (int*)alloc(NN * 4);
  int* col_f  = (int*)alloc((size_t)NE * 4);
  float* wn_f = (float*)alloc((size_t)NE * 4);
  int* col_b  = (int*)alloc((size_t)NE * 4);
  float* wn_b = (float*)alloc((size_t)NE * 4);
  float* Wcat = (float*)alloc(64 * 128 * 4);
  float* cbv  = (float*)alloc(32 * 4);
  float* W2   = (float*)alloc(384 * 4);

  hipMemsetAsync(zreg, 0, 4 * NN * 4, stream);
  deg_kernel<<<(NE + 255) / 256, 256, 0, stream>>>(ei, ew, wsum_f, wsum_b, cnt_f, cnt_b);
  scan_kernel<<<1, 1024, 0, stream>>>(cnt_f, cnt_b, rp_f, rp_b, cur_f, cur_b);
  fill_kernel<<<(NE + 255) / 256, 256, 0, stream>>>(ei, ew, wsum_f, wsum_b, cur_f, cur_b,
                                                    col_f, wn_f, col_b, wn_b);
  nb_kernel<<<NN / 8 + 17, 512, 0, stream>>>(node_emb, enc_b, w_ih, b_ih, enc_w, b_hh,
                                             filt_w, filt_b, dec_w, dec_b,
                                             nbq, W2, Wcat, cbv);
  gru_kernel<<<(NB * NN) / 64, 256, 0, stream>>>(x, nbq, W2, b_hh, w_hh, Wcat, cbv,
                                                 G0, G1f, G2f, G1b, G2b);
  hop1_kernel<<<2 * NN, 192, 0, stream>>>(G1f, G2f, G1b, G2b,
                                          rp_f, col_f, wn_f, rp_b, col_b, wn_b);
  hop2_kernel<<<NN, 192, 0, stream>>>(G0, G1f, G1b,
                                      rp_f, col_f, wn_f, rp_b, col_b, wn_b);
  reorder_kernel<<<NN / 32, 256, 0, stream>>>(G0, out);
}